// Round 1
// baseline (1172.495 us; speedup 1.0000x reference)
//
#include <hip/hip_runtime.h>
#include <hip/hip_bf16.h>

#define N_NODES 100000
#define N_EDGES 800000
#define D 128
#define NG 64

// ---------------- degree / norm precompute ----------------

__global__ void deg_kernel(const int* __restrict__ dst, float* __restrict__ deg) {
    int e = blockIdx.x * blockDim.x + threadIdx.x;
    if (e < N_EDGES) {
        unsafeAtomicAdd(&deg[dst[e]], 1.0f);
    }
}

__global__ void dinv_kernel(float* __restrict__ deg_inout) {
    int i = blockIdx.x * blockDim.x + threadIdx.x;
    if (i < N_NODES) {
        // +1 for the self loop; deg>0 always
        deg_inout[i] = rsqrtf(deg_inout[i] + 1.0f);
    }
}

__global__ void norm_kernel(const int* __restrict__ src, const int* __restrict__ dst,
                            const float* __restrict__ dinv, float* __restrict__ norm) {
    int e = blockIdx.x * blockDim.x + threadIdx.x;
    if (e < N_EDGES) {
        norm[e] = dinv[src[e]] * dinv[dst[e]];
    }
}

// ---------------- dense transform: out = X @ W ----------------
// 128 threads/block, thread f holds W column f in 128 VGPRs.
// x row staged in LDS, read back as float4 broadcasts (4 fma per ds_read_b128).

__global__ __launch_bounds__(128) void xw_kernel(const float* __restrict__ X,
                                                 const float* __restrict__ W,
                                                 float* __restrict__ out, int n) {
    __shared__ __align__(16) float xs[D];
    const int f = threadIdx.x;
    float wcol[D];
#pragma unroll
    for (int k = 0; k < D; ++k) wcol[k] = W[k * D + f];

    for (int node = blockIdx.x; node < n; node += gridDim.x) {
        __syncthreads();
        xs[f] = X[node * D + f];
        __syncthreads();
        float acc = 0.f;
#pragma unroll
        for (int k = 0; k < D; k += 4) {
            float4 xv = *(const float4*)&xs[k];
            acc += xv.x * wcol[k] + xv.y * wcol[k + 1] + xv.z * wcol[k + 2] + xv.w * wcol[k + 3];
        }
        out[node * D + f] = acc;
    }
}

// ---------------- edge scatter: agg[dst] += H[src] * norm ----------------
// thread = (edge, feature): e wave-uniform, f lane-contiguous -> coalesced.

__global__ void scatter_kernel(const float* __restrict__ H,
                               const int* __restrict__ src, const int* __restrict__ dst,
                               const float* __restrict__ norm, float* __restrict__ agg) {
    unsigned idx = blockIdx.x * blockDim.x + threadIdx.x;
    if (idx < (unsigned)N_EDGES * D) {
        int e = idx >> 7;
        int f = idx & (D - 1);
        int s = src[e], d = dst[e];
        float v = H[s * D + f] * norm[e];
        unsafeAtomicAdd(&agg[d * D + f], v);
    }
}

// ---------------- epilogue: out = relu(agg + hw*dinv^2 + b) ----------------

__global__ void epilogue_kernel(const float* __restrict__ agg, const float* __restrict__ HW,
                                const float* __restrict__ dinv, const float* __restrict__ b,
                                float* __restrict__ out) {
    int i = blockIdx.x * blockDim.x + threadIdx.x;
    if (i < N_NODES * D) {
        int node = i >> 7;
        int f = i & (D - 1);
        float di = dinv[node];
        float v = agg[i] + HW[i] * di * di + b[f];
        out[i] = fmaxf(v, 0.f);
    }
}

// ---------------- mean pool over sorted batch ids ----------------
// 128 threads/block, contiguous node chunk, run-length accumulate per graph id.

__global__ void pool_kernel(const float* __restrict__ H, const int* __restrict__ batch,
                            float* __restrict__ sums, float* __restrict__ cnts, int n) {
    int chunk = (n + gridDim.x - 1) / gridDim.x;
    int n0 = blockIdx.x * chunk;
    int n1 = min(n, n0 + chunk);
    if (n0 >= n1) return;
    int f = threadIdx.x;
    float acc = 0.f, cnt = 0.f;
    int g = batch[n0];
    for (int node = n0; node < n1; ++node) {
        int gg = batch[node];
        if (gg != g) {
            unsafeAtomicAdd(&sums[g * D + f], acc);
            if (f == 0) unsafeAtomicAdd(&cnts[g], cnt);
            acc = 0.f; cnt = 0.f; g = gg;
        }
        acc += H[node * D + f];
        cnt += 1.f;
    }
    unsafeAtomicAdd(&sums[g * D + f], acc);
    if (f == 0) unsafeAtomicAdd(&cnts[g], cnt);
}

// ---------------- final FC: out = (sums/cnt) @ Wfc + bfc ----------------

__global__ void fc_kernel(const float* __restrict__ sums, const float* __restrict__ cnts,
                          const float* __restrict__ Wfc, const float* __restrict__ bfc,
                          float* __restrict__ out) {
    __shared__ __align__(16) float ps[D];
    int g = blockIdx.x;
    int f = threadIdx.x;
    float c = fmaxf(cnts[g], 1.f);
    ps[f] = sums[g * D + f] / c;
    __syncthreads();
    float acc = bfc[f];
#pragma unroll
    for (int k = 0; k < D; k += 4) {
        float4 pv = *(const float4*)&ps[k];
        acc += pv.x * Wfc[k * D + f] + pv.y * Wfc[(k + 1) * D + f] +
               pv.z * Wfc[(k + 2) * D + f] + pv.w * Wfc[(k + 3) * D + f];
    }
    out[g * D + f] = acc;
}

extern "C" void kernel_launch(void* const* d_in, const int* in_sizes, int n_in,
                              void* d_out, int out_size, void* d_ws, size_t ws_size,
                              hipStream_t stream) {
    const float* x   = (const float*)d_in[0];
    const int* ei    = (const int*)d_in[1];   // [2, E] row-major
    const int* batch = (const int*)d_in[2];
    const float* W1  = (const float*)d_in[3];
    const float* b1  = (const float*)d_in[4];
    const float* W2  = (const float*)d_in[5];
    const float* b2  = (const float*)d_in[6];
    const float* Wfc = (const float*)d_in[7];
    const float* bfc = (const float*)d_in[8];
    float* out = (float*)d_out;

    const int* src = ei;
    const int* dst = ei + N_EDGES;

    float* bufA = (float*)d_ws;                 // N*D  (hw)
    float* bufB = bufA + (size_t)N_NODES * D;   // N*D  (agg / h)
    float* dinv = bufB + (size_t)N_NODES * D;   // N    (deg, then dinv in place)
    float* norm = dinv + N_NODES;               // E
    float* sums = norm + N_EDGES;               // NG*D
    float* cnts = sums + NG * D;                // NG

    // --- degree / dinv / per-edge norm ---
    hipMemsetAsync(dinv, 0, N_NODES * sizeof(float), stream);
    deg_kernel<<<(N_EDGES + 255) / 256, 256, 0, stream>>>(dst, dinv);
    dinv_kernel<<<(N_NODES + 255) / 256, 256, 0, stream>>>(dinv);
    norm_kernel<<<(N_EDGES + 255) / 256, 256, 0, stream>>>(src, dst, dinv, norm);

    // --- layer 1 ---
    xw_kernel<<<2048, 128, 0, stream>>>(x, W1, bufA, N_NODES);
    hipMemsetAsync(bufB, 0, (size_t)N_NODES * D * sizeof(float), stream);
    scatter_kernel<<<(N_EDGES * D) / 256, 256, 0, stream>>>(bufA, src, dst, norm, bufB);
    epilogue_kernel<<<(N_NODES * D + 255) / 256, 256, 0, stream>>>(bufB, bufA, dinv, b1, bufB);

    // --- layer 2 ---
    xw_kernel<<<2048, 128, 0, stream>>>(bufB, W2, bufA, N_NODES);
    hipMemsetAsync(bufB, 0, (size_t)N_NODES * D * sizeof(float), stream);
    scatter_kernel<<<(N_EDGES * D) / 256, 256, 0, stream>>>(bufA, src, dst, norm, bufB);
    epilogue_kernel<<<(N_NODES * D + 255) / 256, 256, 0, stream>>>(bufB, bufA, dinv, b2, bufB);

    // --- mean pool + FC ---
    hipMemsetAsync(sums, 0, (NG * D + NG) * sizeof(float), stream);
    pool_kernel<<<512, 128, 0, stream>>>(bufB, batch, sums, cnts, N_NODES);
    fc_kernel<<<NG, 128, 0, stream>>>(sums, cnts, Wfc, bfc, out);
}

// Round 2
// 494.196 us; speedup vs baseline: 2.3725x; 2.3725x over previous
//
#include <hip/hip_runtime.h>
#include <hip/hip_bf16.h>

#define N_NODES 100000
#define N_EDGES 800000
#define D 128
#define NG 64
#define SCAN_NB ((N_NODES + 255) / 256)   // 391

// ---------------- CSR build: histogram / dinv / scan / fill ----------------

__global__ void hist_kernel(const int* __restrict__ dst, int* __restrict__ deg) {
    int e = blockIdx.x * blockDim.x + threadIdx.x;
    if (e < N_EDGES) atomicAdd(&deg[dst[e]], 1);
}

__global__ void dinv_kernel(const int* __restrict__ deg, float* __restrict__ dinv) {
    int i = blockIdx.x * blockDim.x + threadIdx.x;
    if (i < N_NODES) dinv[i] = rsqrtf((float)deg[i] + 1.0f);  // +1 self loop
}

// block-level exclusive scan of deg -> rs, block totals -> bsum
__global__ __launch_bounds__(256) void scan1_kernel(const int* __restrict__ deg,
                                                    int* __restrict__ rs,
                                                    int* __restrict__ bsum) {
    __shared__ int wsum[4];
    int i = blockIdx.x * 256 + threadIdx.x;
    int lane = threadIdx.x & 63;
    int wid = threadIdx.x >> 6;
    int v = (i < N_NODES) ? deg[i] : 0;
    int x = v;
    #pragma unroll
    for (int off = 1; off < 64; off <<= 1) {
        int y = __shfl_up(x, off);
        if (lane >= off) x += y;
    }
    if (lane == 63) wsum[wid] = x;
    __syncthreads();
    int add = 0;
    #pragma unroll
    for (int w = 0; w < 3; ++w) if (w < wid) add += wsum[w];
    int incl = x + add;
    if (i < N_NODES) rs[i] = incl - v;  // exclusive within block
    if (threadIdx.x == 255) bsum[blockIdx.x] = incl;
}

__global__ __launch_bounds__(512) void scan2_kernel(int* __restrict__ bsum) {
    __shared__ int s[512];
    int t = threadIdx.x;
    int v = (t < SCAN_NB) ? bsum[t] : 0;
    s[t] = v;
    __syncthreads();
    for (int off = 1; off < 512; off <<= 1) {
        int y = (t >= off) ? s[t - off] : 0;
        __syncthreads();
        s[t] += y;
        __syncthreads();
    }
    if (t < SCAN_NB) bsum[t] = s[t] - v;  // exclusive block offsets
}

__global__ void scan3_kernel(int* __restrict__ rs, const int* __restrict__ bsum) {
    int i = blockIdx.x * blockDim.x + threadIdx.x;
    if (i < N_NODES) rs[i] += bsum[i >> 8];
    if (i == 0) rs[N_NODES] = N_EDGES;
}

__global__ void fill_kernel(const int* __restrict__ src, const int* __restrict__ dst,
                            const float* __restrict__ dinv, const int* __restrict__ rs,
                            int* __restrict__ cursor, int2* __restrict__ pairs) {
    int e = blockIdx.x * blockDim.x + threadIdx.x;
    if (e < N_EDGES) {
        int d = dst[e];
        int s = src[e];
        int p = rs[d] + atomicAdd(&cursor[d], 1);
        pairs[p] = make_int2(s, __float_as_int(dinv[s] * dinv[d]));
    }
}

// ---------------- dense transform: out = X @ W ----------------
// 512 threads = 8 waves. lane = node (64 nodes/block), wave w computes
// features w*16..w*16+15. X tile staged in LDS with XOR swizzle
// (conflict-free ds_read_b128); W read via wave-uniform scalar loads.

__global__ __launch_bounds__(512) void xw_kernel(const float* __restrict__ X,
                                                 const float* __restrict__ W,
                                                 float* __restrict__ out, int n) {
    __shared__ __align__(16) float xs[64 * 128];  // 32 KB
    const int t = threadIdx.x;
    const int lane = t & 63;
    const int wid = t >> 6;
    const int node0 = blockIdx.x * 64;

    // stage X[node0 .. node0+64) -> xs (swizzled)
    #pragma unroll
    for (int i = 0; i < 4; ++i) {
        int j = t + i * 512;            // float4 id in [0,2048)
        int row = j >> 5;
        int c4 = (j & 31) * 4;
        int srcnode = node0 + row;
        float4 v = make_float4(0.f, 0.f, 0.f, 0.f);
        if (srcnode < n) v = *(const float4*)&X[(size_t)srcnode * 128 + c4];
        int sw = c4 ^ ((row & 7) << 2);
        *(float4*)&xs[row * 128 + sw] = v;
    }
    __syncthreads();

    const int f0 = __builtin_amdgcn_readfirstlane(wid) * 16;
    const float* Wp = W + f0;
    float acc[16];
    #pragma unroll
    for (int f = 0; f < 16; ++f) acc[f] = 0.f;

    const int swl = (lane & 7) << 2;
    #pragma unroll 4
    for (int kb = 0; kb < 128; kb += 4) {
        float4 xv = *(const float4*)&xs[lane * 128 + (kb ^ swl)];
        #pragma unroll
        for (int j = 0; j < 4; ++j) {
            const float* wr = Wp + (kb + j) * 128;  // uniform address -> s_load
            float xk = (&xv.x)[j];
            #pragma unroll
            for (int f = 0; f < 16; ++f) acc[f] = fmaf(xk, wr[f], acc[f]);
        }
    }

    // transpose through LDS for coalesced stores
    __syncthreads();
    #pragma unroll
    for (int c = 0; c < 16; c += 4) {
        int col = f0 + c;
        int sw = col ^ swl;
        *(float4*)&xs[lane * 128 + sw] = make_float4(acc[c], acc[c + 1], acc[c + 2], acc[c + 3]);
    }
    __syncthreads();
    #pragma unroll
    for (int i = 0; i < 4; ++i) {
        int j = t + i * 512;
        int row = j >> 5;
        int c4 = (j & 31) * 4;
        int node = node0 + row;
        if (node < n) {
            int sw = c4 ^ ((row & 7) << 2);
            *(float4*)&out[(size_t)node * 128 + c4] = *(const float4*)&xs[row * 128 + sw];
        }
    }
}

// ---------------- CSR gather + fused epilogue ----------------
// wave per node, lane f handles features 2f,2f+1:
// out[n] = relu( sum_{e in in(n)} H[src_e]*norm_e + H[n]*dinv[n]^2 + b )

__global__ __launch_bounds__(256) void gather_kernel(const float* __restrict__ H,
                                                     const int* __restrict__ rs,
                                                     const int2* __restrict__ pairs,
                                                     const float* __restrict__ dinv,
                                                     const float* __restrict__ bias,
                                                     float* __restrict__ out) {
    int node = blockIdx.x * 4 + (threadIdx.x >> 6);
    if (node >= N_NODES) return;
    int lane = threadIdx.x & 63;

    float di = dinv[node];
    float2 acc = *(const float2*)&H[(size_t)node * 128 + lane * 2];
    float2 bb = *(const float2*)&bias[lane * 2];
    acc.x = acc.x * di * di + bb.x;
    acc.y = acc.y * di * di + bb.y;

    int beg = rs[node];
    int end = rs[node + 1];
    int i = beg;
    for (; i + 1 < end; i += 2) {
        int2 p0 = pairs[i];
        int2 p1 = pairs[i + 1];
        float2 h0 = *(const float2*)&H[(size_t)p0.x * 128 + lane * 2];
        float2 h1 = *(const float2*)&H[(size_t)p1.x * 128 + lane * 2];
        float w0 = __int_as_float(p0.y);
        float w1 = __int_as_float(p1.y);
        acc.x = fmaf(h0.x, w0, acc.x);
        acc.y = fmaf(h0.y, w0, acc.y);
        acc.x = fmaf(h1.x, w1, acc.x);
        acc.y = fmaf(h1.y, w1, acc.y);
    }
    if (i < end) {
        int2 p = pairs[i];
        float w = __int_as_float(p.y);
        float2 h = *(const float2*)&H[(size_t)p.x * 128 + lane * 2];
        acc.x = fmaf(h.x, w, acc.x);
        acc.y = fmaf(h.y, w, acc.y);
    }
    acc.x = fmaxf(acc.x, 0.f);
    acc.y = fmaxf(acc.y, 0.f);
    *(float2*)&out[(size_t)node * 128 + lane * 2] = acc;
}

// ---------------- mean pool over sorted batch ids ----------------

__global__ void pool_kernel(const float* __restrict__ H, const int* __restrict__ batch,
                            float* __restrict__ sums, float* __restrict__ cnts, int n) {
    int chunk = (n + gridDim.x - 1) / gridDim.x;
    int n0 = blockIdx.x * chunk;
    int n1 = min(n, n0 + chunk);
    if (n0 >= n1) return;
    int f = threadIdx.x;
    float acc = 0.f, cnt = 0.f;
    int g = batch[n0];
    for (int node = n0; node < n1; ++node) {
        int gg = batch[node];
        if (gg != g) {
            unsafeAtomicAdd(&sums[g * D + f], acc);
            if (f == 0) unsafeAtomicAdd(&cnts[g], cnt);
            acc = 0.f; cnt = 0.f; g = gg;
        }
        acc += H[node * D + f];
        cnt += 1.f;
    }
    unsafeAtomicAdd(&sums[g * D + f], acc);
    if (f == 0) unsafeAtomicAdd(&cnts[g], cnt);
}

// ---------------- final FC ----------------

__global__ void fc_kernel(const float* __restrict__ sums, const float* __restrict__ cnts,
                          const float* __restrict__ Wfc, const float* __restrict__ bfc,
                          float* __restrict__ out) {
    __shared__ __align__(16) float ps[D];
    int g = blockIdx.x;
    int f = threadIdx.x;
    float c = fmaxf(cnts[g], 1.f);
    ps[f] = sums[g * D + f] / c;
    __syncthreads();
    float acc = bfc[f];
    #pragma unroll
    for (int k = 0; k < D; k += 4) {
        float4 pv = *(const float4*)&ps[k];
        acc += pv.x * Wfc[k * D + f] + pv.y * Wfc[(k + 1) * D + f] +
               pv.z * Wfc[(k + 2) * D + f] + pv.w * Wfc[(k + 3) * D + f];
    }
    out[g * D + f] = acc;
}

extern "C" void kernel_launch(void* const* d_in, const int* in_sizes, int n_in,
                              void* d_out, int out_size, void* d_ws, size_t ws_size,
                              hipStream_t stream) {
    const float* x   = (const float*)d_in[0];
    const int* ei    = (const int*)d_in[1];   // [2, E]
    const int* batch = (const int*)d_in[2];
    const float* W1  = (const float*)d_in[3];
    const float* b1  = (const float*)d_in[4];
    const float* W2  = (const float*)d_in[5];
    const float* b2  = (const float*)d_in[6];
    const float* Wfc = (const float*)d_in[7];
    const float* bfc = (const float*)d_in[8];
    float* out = (float*)d_out;

    const int* src = ei;
    const int* dst = ei + N_EDGES;

    // workspace layout
    float* bufA   = (float*)d_ws;                      // N*D
    float* bufB   = bufA + (size_t)N_NODES * D;        // N*D
    float* dinv   = bufB + (size_t)N_NODES * D;        // N
    int*   deg    = (int*)(dinv + N_NODES);            // N
    int*   rs     = deg + N_NODES;                     // N+1 (padded to N+4)
    int*   cursor = rs + N_NODES + 4;                  // N
    int*   bsum   = cursor + N_NODES;                  // 512
    int2*  pairs  = (int2*)(bsum + 512);               // E
    float* sums   = (float*)(pairs + N_EDGES);         // NG*D
    float* cnts   = sums + NG * D;                     // NG

    hipMemsetAsync(deg, 0, N_NODES * sizeof(int), stream);
    hipMemsetAsync(cursor, 0, N_NODES * sizeof(int), stream);
    hipMemsetAsync(sums, 0, (NG * D + NG) * sizeof(float), stream);

    // --- CSR build (shared by both layers) ---
    hist_kernel<<<(N_EDGES + 255) / 256, 256, 0, stream>>>(dst, deg);
    dinv_kernel<<<(N_NODES + 255) / 256, 256, 0, stream>>>(deg, dinv);
    scan1_kernel<<<SCAN_NB, 256, 0, stream>>>(deg, rs, bsum);
    scan2_kernel<<<1, 512, 0, stream>>>(bsum);
    scan3_kernel<<<SCAN_NB, 256, 0, stream>>>(rs, bsum);
    fill_kernel<<<(N_EDGES + 255) / 256, 256, 0, stream>>>(src, dst, dinv, rs, cursor, pairs);

    // --- layer 1 ---
    xw_kernel<<<(N_NODES + 63) / 64, 512, 0, stream>>>(x, W1, bufA, N_NODES);
    gather_kernel<<<(N_NODES + 3) / 4, 256, 0, stream>>>(bufA, rs, pairs, dinv, b1, bufB);

    // --- layer 2 ---
    xw_kernel<<<(N_NODES + 63) / 64, 512, 0, stream>>>(bufB, W2, bufA, N_NODES);
    gather_kernel<<<(N_NODES + 3) / 4, 256, 0, stream>>>(bufA, rs, pairs, dinv, b2, bufB);

    // --- mean pool + FC ---
    pool_kernel<<<512, 128, 0, stream>>>(bufB, batch, sums, cnts, N_NODES);
    fc_kernel<<<NG, 128, 0, stream>>>(sums, cnts, Wfc, bfc, out);
}

// Round 3
// 381.952 us; speedup vs baseline: 3.0697x; 1.2939x over previous
//
#include <hip/hip_runtime.h>
#include <hip/hip_bf16.h>

#define N_NODES 100000
#define N_EDGES 800000
#define D 128
#define NG 64
#define SCAN_NB ((N_NODES + 255) / 256)   // 391
#define NTILES ((N_NODES + 63) / 64)      // 1563

typedef __attribute__((ext_vector_type(8))) short short8;
typedef __attribute__((ext_vector_type(4))) float f32x4;

static __device__ __forceinline__ unsigned short f2bf(float f) {
    unsigned u = __float_as_uint(f);
    unsigned r = (u + 0x7FFF + ((u >> 16) & 1)) >> 16;   // RTN-even
    return (unsigned short)r;
}
static __device__ __forceinline__ float bf2f(unsigned short b) {
    return __uint_as_float((unsigned)b << 16);
}

// ---------------- CSR build: histogram / dinv / scan / fill ----------------

__global__ void hist_kernel(const int* __restrict__ dst, int* __restrict__ deg) {
    int e = blockIdx.x * blockDim.x + threadIdx.x;
    if (e < N_EDGES) atomicAdd(&deg[dst[e]], 1);
}

__global__ void dinv_kernel(const int* __restrict__ deg, float* __restrict__ dinv) {
    int i = blockIdx.x * blockDim.x + threadIdx.x;
    if (i < N_NODES) dinv[i] = rsqrtf((float)deg[i] + 1.0f);  // +1 self loop
}

__global__ __launch_bounds__(256) void scan1_kernel(const int* __restrict__ deg,
                                                    int* __restrict__ rs,
                                                    int* __restrict__ bsum) {
    __shared__ int wsum[4];
    int i = blockIdx.x * 256 + threadIdx.x;
    int lane = threadIdx.x & 63;
    int wid = threadIdx.x >> 6;
    int v = (i < N_NODES) ? deg[i] : 0;
    int x = v;
    #pragma unroll
    for (int off = 1; off < 64; off <<= 1) {
        int y = __shfl_up(x, off);
        if (lane >= off) x += y;
    }
    if (lane == 63) wsum[wid] = x;
    __syncthreads();
    int add = 0;
    #pragma unroll
    for (int w = 0; w < 3; ++w) if (w < wid) add += wsum[w];
    int incl = x + add;
    if (i < N_NODES) rs[i] = incl - v;
    if (threadIdx.x == 255) bsum[blockIdx.x] = incl;
}

__global__ __launch_bounds__(512) void scan2_kernel(int* __restrict__ bsum) {
    __shared__ int s[512];
    int t = threadIdx.x;
    int v = (t < SCAN_NB) ? bsum[t] : 0;
    s[t] = v;
    __syncthreads();
    for (int off = 1; off < 512; off <<= 1) {
        int y = (t >= off) ? s[t - off] : 0;
        __syncthreads();
        s[t] += y;
        __syncthreads();
    }
    if (t < SCAN_NB) bsum[t] = s[t] - v;
}

__global__ void scan3_kernel(int* __restrict__ rs, const int* __restrict__ bsum) {
    int i = blockIdx.x * blockDim.x + threadIdx.x;
    if (i < N_NODES) rs[i] += bsum[i >> 8];
    if (i == 0) rs[N_NODES] = N_EDGES;
}

__global__ void fill_kernel(const int* __restrict__ src, const int* __restrict__ dst,
                            const float* __restrict__ dinv, const int* __restrict__ rs,
                            int* __restrict__ cursor, int2* __restrict__ pairs) {
    int e = blockIdx.x * blockDim.x + threadIdx.x;
    if (e < N_EDGES) {
        int d = dst[e];
        int s = src[e];
        int p = rs[d] + atomicAdd(&cursor[d], 1);
        pairs[p] = make_int2(s, __float_as_int(dinv[s] * dinv[d]));
    }
}

// ---------------- dense transform via MFMA: Hout = bf16( A @ (Whi+Wlo) ) ----
// block = 512 thr = 8 waves (4M x 2N wave grid), tile = 64 nodes x 128 feats.
// W staged once per block (hi/lo, transposed, XOR-swizzled); A tile per iter.
// 16x16x32 bf16 MFMA; verified layouts: A lane l = A[l&15][(l>>4)*8+e],
// B lane l = B[(l>>4)*8+e][l&15], C lane l reg r = C[(l>>4)*4+r][l&15].

template <bool IN_F32>
__global__ __launch_bounds__(512) void xw_mfma_kernel(const void* __restrict__ Xin,
                                                      const float* __restrict__ W,
                                                      unsigned short* __restrict__ Hout) {
    __shared__ __align__(16) unsigned short bt_hi[128 * 128];  // 32 KB, Bt[n][k]
    __shared__ __align__(16) unsigned short bt_lo[128 * 128];  // 32 KB
    __shared__ __align__(16) unsigned short atile[64 * 128];   // 16 KB, A[row][k]

    const int t = threadIdx.x;
    const int lane = t & 63;
    const int wid = t >> 6;

    // ---- stage W hi/lo transposed (once per block) ----
    #pragma unroll 4
    for (int i = 0; i < 32; ++i) {
        int idx = t + i * 512;           // 0..16383
        int k = idx >> 7;
        int n = idx & 127;
        float w = W[idx];                // W[k][n], coalesced over n
        unsigned short hi = f2bf(w);
        unsigned short lo = f2bf(w - bf2f(hi));
        int byte = (n * 256 + k * 2) ^ ((n & 7) << 4);
        *(unsigned short*)((char*)bt_hi + byte) = hi;
        *(unsigned short*)((char*)bt_lo + byte) = lo;
    }

    const int mrow = (wid >> 1) * 16;
    const int ncol = (wid & 1) * 64;
    const int ar = mrow + (lane & 15);
    const int ak = (lane >> 4) * 8;

    for (int tile = blockIdx.x; tile < NTILES; tile += gridDim.x) {
        const int node0 = tile * 64;
        __syncthreads();   // W ready (iter 0) / prev iter's LDS reads done

        // ---- stage A tile (64 x 128), cast to bf16 if needed ----
        #pragma unroll
        for (int p = 0; p < 2; ++p) {
            int j = t + p * 512;         // 0..1023
            int row = j >> 4;
            int c8 = (j & 15) * 8;
            int node = node0 + row;
            short8 v = 0;
            if (IN_F32) {
                const float* X = (const float*)Xin;
                if (node < N_NODES) {
                    const float* xr = &X[(size_t)node * 128 + c8];
                    float4 a = *(const float4*)xr;
                    float4 b = *(const float4*)(xr + 4);
                    v[0] = (short)f2bf(a.x); v[1] = (short)f2bf(a.y);
                    v[2] = (short)f2bf(a.z); v[3] = (short)f2bf(a.w);
                    v[4] = (short)f2bf(b.x); v[5] = (short)f2bf(b.y);
                    v[6] = (short)f2bf(b.z); v[7] = (short)f2bf(b.w);
                }
            } else {
                const unsigned short* X = (const unsigned short*)Xin;
                if (node < N_NODES) v = *(const short8*)&X[(size_t)node * 128 + c8];
            }
            int byte = (row * 256 + c8 * 2) ^ ((row & 7) << 4);
            *(short8*)((char*)atile + byte) = v;
        }
        __syncthreads();

        // ---- MFMA: 4 k-chunks x 4 n-tiles x (hi+lo) ----
        f32x4 acc[4];
        #pragma unroll
        for (int nt = 0; nt < 4; ++nt) acc[nt] = 0.f;

        #pragma unroll
        for (int kc = 0; kc < 128; kc += 32) {
            short8 a = *(const short8*)((const char*)atile +
                        ((ar * 256 + (kc + ak) * 2) ^ ((ar & 7) << 4)));
            #pragma unroll
            for (int nt = 0; nt < 4; ++nt) {
                int col = ncol + nt * 16 + (lane & 15);
                int boff = (col * 256 + (kc + ak) * 2) ^ ((col & 7) << 4);
                short8 bh = *(const short8*)((const char*)bt_hi + boff);
                acc[nt] = __builtin_amdgcn_mfma_f32_16x16x32_bf16(a, bh, acc[nt], 0, 0, 0);
                short8 bl = *(const short8*)((const char*)bt_lo + boff);
                acc[nt] = __builtin_amdgcn_mfma_f32_16x16x32_bf16(a, bl, acc[nt], 0, 0, 0);
            }
        }

        // ---- store C as bf16 ----
        #pragma unroll
        for (int nt = 0; nt < 4; ++nt) {
            #pragma unroll
            for (int r = 0; r < 4; ++r) {
                int node = node0 + mrow + (lane >> 4) * 4 + r;
                if (node < N_NODES)
                    Hout[(size_t)node * 128 + ncol + nt * 16 + (lane & 15)] = f2bf(acc[nt][r]);
            }
        }
    }
}

// ---------------- CSR gather (bf16 in/out) + fused epilogue ----------------
// wave per node, lane f handles features 2f,2f+1 (ushort2 = 4 B/lane).

__global__ __launch_bounds__(256) void gather_kernel(const unsigned short* __restrict__ H,
                                                     const int* __restrict__ rs,
                                                     const int2* __restrict__ pairs,
                                                     const float* __restrict__ dinv,
                                                     const float* __restrict__ bias,
                                                     unsigned short* __restrict__ out) {
    int node = blockIdx.x * 4 + (threadIdx.x >> 6);
    if (node >= N_NODES) return;
    int lane = threadIdx.x & 63;

    float di = dinv[node];
    ushort2 hv = *(const ushort2*)&H[(size_t)node * 128 + lane * 2];
    float2 bb = *(const float2*)&bias[lane * 2];
    float ax = bf2f(hv.x) * di * di + bb.x;
    float ay = bf2f(hv.y) * di * di + bb.y;

    int beg = rs[node];
    int end = rs[node + 1];
    int i = beg;
    for (; i + 3 < end; i += 4) {
        int2 p0 = pairs[i];
        int2 p1 = pairs[i + 1];
        int2 p2 = pairs[i + 2];
        int2 p3 = pairs[i + 3];
        ushort2 h0 = *(const ushort2*)&H[(size_t)p0.x * 128 + lane * 2];
        ushort2 h1 = *(const ushort2*)&H[(size_t)p1.x * 128 + lane * 2];
        ushort2 h2 = *(const ushort2*)&H[(size_t)p2.x * 128 + lane * 2];
        ushort2 h3 = *(const ushort2*)&H[(size_t)p3.x * 128 + lane * 2];
        float w0 = __int_as_float(p0.y), w1 = __int_as_float(p1.y);
        float w2 = __int_as_float(p2.y), w3 = __int_as_float(p3.y);
        ax = fmaf(bf2f(h0.x), w0, ax); ay = fmaf(bf2f(h0.y), w0, ay);
        ax = fmaf(bf2f(h1.x), w1, ax); ay = fmaf(bf2f(h1.y), w1, ay);
        ax = fmaf(bf2f(h2.x), w2, ax); ay = fmaf(bf2f(h2.y), w2, ay);
        ax = fmaf(bf2f(h3.x), w3, ax); ay = fmaf(bf2f(h3.y), w3, ay);
    }
    for (; i < end; ++i) {
        int2 p = pairs[i];
        float w = __int_as_float(p.y);
        ushort2 h = *(const ushort2*)&H[(size_t)p.x * 128 + lane * 2];
        ax = fmaf(bf2f(h.x), w, ax);
        ay = fmaf(bf2f(h.y), w, ay);
    }
    ushort2 o;
    o.x = f2bf(fmaxf(ax, 0.f));
    o.y = f2bf(fmaxf(ay, 0.f));
    *(ushort2*)&out[(size_t)node * 128 + lane * 2] = o;
}

// ---------------- mean pool over sorted batch ids (bf16 input) -------------

__global__ void pool_kernel(const unsigned short* __restrict__ H, const int* __restrict__ batch,
                            float* __restrict__ sums, float* __restrict__ cnts, int n) {
    int chunk = (n + gridDim.x - 1) / gridDim.x;
    int n0 = blockIdx.x * chunk;
    int n1 = min(n, n0 + chunk);
    if (n0 >= n1) return;
    int f = threadIdx.x;
    float acc = 0.f, cnt = 0.f;
    int g = batch[n0];
    for (int node = n0; node < n1; ++node) {
        int gg = batch[node];
        if (gg != g) {
            unsafeAtomicAdd(&sums[g * D + f], acc);
            if (f == 0) unsafeAtomicAdd(&cnts[g], cnt);
            acc = 0.f; cnt = 0.f; g = gg;
        }
        acc += bf2f(H[(size_t)node * D + f]);
        cnt += 1.f;
    }
    unsafeAtomicAdd(&sums[g * D + f], acc);
    if (f == 0) unsafeAtomicAdd(&cnts[g], cnt);
}

// ---------------- final FC ----------------

__global__ void fc_kernel(const float* __restrict__ sums, const float* __restrict__ cnts,
                          const float* __restrict__ Wfc, const float* __restrict__ bfc,
                          float* __restrict__ out) {
    __shared__ __align__(16) float ps[D];
    int g = blockIdx.x;
    int f = threadIdx.x;
    float c = fmaxf(cnts[g], 1.f);
    ps[f] = sums[g * D + f] / c;
    __syncthreads();
    float acc = bfc[f];
    #pragma unroll
    for (int k = 0; k < D; k += 4) {
        float4 pv = *(const float4*)&ps[k];
        acc += pv.x * Wfc[k * D + f] + pv.y * Wfc[(k + 1) * D + f] +
               pv.z * Wfc[(k + 2) * D + f] + pv.w * Wfc[(k + 3) * D + f];
    }
    out[g * D + f] = acc;
}

extern "C" void kernel_launch(void* const* d_in, const int* in_sizes, int n_in,
                              void* d_out, int out_size, void* d_ws, size_t ws_size,
                              hipStream_t stream) {
    const float* x   = (const float*)d_in[0];
    const int* ei    = (const int*)d_in[1];   // [2, E]
    const int* batch = (const int*)d_in[2];
    const float* W1  = (const float*)d_in[3];
    const float* b1  = (const float*)d_in[4];
    const float* W2  = (const float*)d_in[5];
    const float* b2  = (const float*)d_in[6];
    const float* Wfc = (const float*)d_in[7];
    const float* bfc = (const float*)d_in[8];
    float* out = (float*)d_out;

    const int* src = ei;
    const int* dst = ei + N_EDGES;

    // workspace layout
    int2* pairs          = (int2*)d_ws;                          // E
    unsigned short* H1   = (unsigned short*)(pairs + N_EDGES);   // N*D bf16
    unsigned short* H2   = H1 + (size_t)N_NODES * D;             // N*D bf16
    float* dinv          = (float*)(H2 + (size_t)N_NODES * D);   // N
    int*   deg           = (int*)(dinv + N_NODES);               // N
    int*   rs            = deg + N_NODES;                        // N+4
    int*   cursor        = rs + N_NODES + 4;                     // N
    int*   bsum          = cursor + N_NODES;                     // 512
    float* sums          = (float*)(bsum + 512);                 // NG*D
    float* cnts          = sums + NG * D;                        // NG

    hipMemsetAsync(deg, 0, N_NODES * sizeof(int), stream);
    hipMemsetAsync(cursor, 0, N_NODES * sizeof(int), stream);
    hipMemsetAsync(sums, 0, (NG * D + NG) * sizeof(float), stream);

    // --- CSR build (shared by both layers) ---
    hist_kernel<<<(N_EDGES + 255) / 256, 256, 0, stream>>>(dst, deg);
    dinv_kernel<<<(N_NODES + 255) / 256, 256, 0, stream>>>(deg, dinv);
    scan1_kernel<<<SCAN_NB, 256, 0, stream>>>(deg, rs, bsum);
    scan2_kernel<<<1, 512, 0, stream>>>(bsum);
    scan3_kernel<<<SCAN_NB, 256, 0, stream>>>(rs, bsum);
    fill_kernel<<<(N_EDGES + 255) / 256, 256, 0, stream>>>(src, dst, dinv, rs, cursor, pairs);

    // --- layer 1 ---
    xw_mfma_kernel<true><<<512, 512, 0, stream>>>(x, W1, H1);
    gather_kernel<<<(N_NODES + 3) / 4, 256, 0, stream>>>(H1, rs, pairs, dinv, b1, H2);

    // --- layer 2 ---
    xw_mfma_kernel<false><<<512, 512, 0, stream>>>(H2, W2, H1);
    gather_kernel<<<(N_NODES + 3) / 4, 256, 0, stream>>>(H1, rs, pairs, dinv, b2, H2);

    // --- mean pool + FC ---
    pool_kernel<<<512, 128, 0, stream>>>(H2, batch, sums, cnts, N_NODES);
    fc_kernel<<<NG, 128, 0, stream>>>(sums, cnts, Wfc, bfc, out);
}

// Round 4
// 336.461 us; speedup vs baseline: 3.4848x; 1.1352x over previous
//
#include <hip/hip_runtime.h>
#include <hip/hip_bf16.h>

#define N_NODES 100000
#define N_EDGES 800000
#define D 128
#define NG 64
#define SCAN_NB ((N_NODES + 255) / 256)   // 391
#define NTILES ((N_NODES + 63) / 64)      // 1563

typedef __attribute__((ext_vector_type(8))) short short8;
typedef __attribute__((ext_vector_type(4))) float f32x4;

static __device__ __forceinline__ unsigned short f2bf(float f) {
    unsigned u = __float_as_uint(f);
    unsigned r = (u + 0x7FFF + ((u >> 16) & 1)) >> 16;   // RTN-even
    return (unsigned short)r;
}
static __device__ __forceinline__ float bf2f(unsigned short b) {
    return __uint_as_float((unsigned)b << 16);
}

// ---------------- CSR build: histogram / dinv / scan / fill ----------------

__global__ void hist_kernel(const int* __restrict__ dst, int* __restrict__ deg) {
    int e = blockIdx.x * blockDim.x + threadIdx.x;
    if (e < N_EDGES) atomicAdd(&deg[dst[e]], 1);
}

__global__ void dinv_kernel(const int* __restrict__ deg, float* __restrict__ dinv) {
    int i = blockIdx.x * blockDim.x + threadIdx.x;
    if (i < N_NODES) dinv[i] = rsqrtf((float)deg[i] + 1.0f);  // +1 self loop
}

__global__ __launch_bounds__(256) void scan1_kernel(const int* __restrict__ deg,
                                                    int* __restrict__ rs,
                                                    int* __restrict__ bsum) {
    __shared__ int wsum[4];
    int i = blockIdx.x * 256 + threadIdx.x;
    int lane = threadIdx.x & 63;
    int wid = threadIdx.x >> 6;
    int v = (i < N_NODES) ? deg[i] : 0;
    int x = v;
    #pragma unroll
    for (int off = 1; off < 64; off <<= 1) {
        int y = __shfl_up(x, off);
        if (lane >= off) x += y;
    }
    if (lane == 63) wsum[wid] = x;
    __syncthreads();
    int add = 0;
    #pragma unroll
    for (int w = 0; w < 3; ++w) if (w < wid) add += wsum[w];
    int incl = x + add;
    if (i < N_NODES) rs[i] = incl - v;
    if (threadIdx.x == 255) bsum[blockIdx.x] = incl;
}

__global__ __launch_bounds__(512) void scan2_kernel(int* __restrict__ bsum) {
    __shared__ int s[512];
    int t = threadIdx.x;
    int v = (t < SCAN_NB) ? bsum[t] : 0;
    s[t] = v;
    __syncthreads();
    for (int off = 1; off < 512; off <<= 1) {
        int y = (t >= off) ? s[t - off] : 0;
        __syncthreads();
        s[t] += y;
        __syncthreads();
    }
    if (t < SCAN_NB) bsum[t] = s[t] - v;
}

__global__ void scan3_kernel(int* __restrict__ rs, const int* __restrict__ bsum) {
    int i = blockIdx.x * blockDim.x + threadIdx.x;
    if (i < N_NODES) rs[i] += bsum[i >> 8];
    if (i == 0) rs[N_NODES] = N_EDGES;
}

__global__ void fill_kernel(const int* __restrict__ src, const int* __restrict__ dst,
                            const float* __restrict__ dinv, const int* __restrict__ rs,
                            int* __restrict__ cursor, int2* __restrict__ pairs) {
    int e = blockIdx.x * blockDim.x + threadIdx.x;
    if (e < N_EDGES) {
        int d = dst[e];
        int s = src[e];
        int p = rs[d] + atomicAdd(&cursor[d], 1);
        pairs[p] = make_int2(s, __float_as_int(dinv[s] * dinv[d]));
    }
}

// ---------------- graph boundaries from sorted batch ----------------

__global__ void bounds_kernel(const int* __restrict__ batch, int* __restrict__ start) {
    int g = threadIdx.x;
    if (g > NG) return;
    if (g == NG) { start[NG] = N_NODES; return; }
    int lo = 0, hi = N_NODES;
    while (lo < hi) {
        int mid = (lo + hi) >> 1;
        if (batch[mid] < g) lo = mid + 1; else hi = mid;
    }
    start[g] = lo;
}

// ---------------- dense transform via MFMA: Hout = bf16( A @ (Whi+Wlo) ) ----

template <bool IN_F32>
__global__ __launch_bounds__(512) void xw_mfma_kernel(const void* __restrict__ Xin,
                                                      const float* __restrict__ W,
                                                      unsigned short* __restrict__ Hout) {
    __shared__ __align__(16) unsigned short bt_hi[128 * 128];  // 32 KB, Bt[n][k]
    __shared__ __align__(16) unsigned short bt_lo[128 * 128];  // 32 KB
    __shared__ __align__(16) unsigned short atile[64 * 128];   // 16 KB, A[row][k]

    const int t = threadIdx.x;
    const int lane = t & 63;
    const int wid = t >> 6;

    // ---- stage W hi/lo transposed (once per block) ----
    #pragma unroll 4
    for (int i = 0; i < 32; ++i) {
        int idx = t + i * 512;           // 0..16383
        int k = idx >> 7;
        int n = idx & 127;
        float w = W[idx];                // W[k][n], coalesced over n
        unsigned short hi = f2bf(w);
        unsigned short lo = f2bf(w - bf2f(hi));
        int byte = (n * 256 + k * 2) ^ ((n & 7) << 4);
        *(unsigned short*)((char*)bt_hi + byte) = hi;
        *(unsigned short*)((char*)bt_lo + byte) = lo;
    }

    const int mrow = (wid >> 1) * 16;
    const int ncol = (wid & 1) * 64;
    const int ar = mrow + (lane & 15);
    const int ak = (lane >> 4) * 8;

    for (int tile = blockIdx.x; tile < NTILES; tile += gridDim.x) {
        const int node0 = tile * 64;
        __syncthreads();   // W ready (iter 0) / prev iter's LDS reads done

        // ---- stage A tile (64 x 128) ----
        #pragma unroll
        for (int p = 0; p < 2; ++p) {
            int j = t + p * 512;         // 0..1023
            int row = j >> 4;
            int c8 = (j & 15) * 8;
            int node = node0 + row;
            short8 v = 0;
            if (IN_F32) {
                const float* X = (const float*)Xin;
                if (node < N_NODES) {
                    const float* xr = &X[(size_t)node * 128 + c8];
                    float4 a = *(const float4*)xr;
                    float4 b = *(const float4*)(xr + 4);
                    v[0] = (short)f2bf(a.x); v[1] = (short)f2bf(a.y);
                    v[2] = (short)f2bf(a.z); v[3] = (short)f2bf(a.w);
                    v[4] = (short)f2bf(b.x); v[5] = (short)f2bf(b.y);
                    v[6] = (short)f2bf(b.z); v[7] = (short)f2bf(b.w);
                }
            } else {
                const unsigned short* X = (const unsigned short*)Xin;
                if (node < N_NODES) v = *(const short8*)&X[(size_t)node * 128 + c8];
            }
            int byte = (row * 256 + c8 * 2) ^ ((row & 7) << 4);
            *(short8*)((char*)atile + byte) = v;
        }
        __syncthreads();

        // ---- MFMA: 4 k-chunks x 4 n-tiles x (hi+lo) ----
        f32x4 acc[4];
        #pragma unroll
        for (int nt = 0; nt < 4; ++nt) acc[nt] = 0.f;

        #pragma unroll
        for (int kc = 0; kc < 128; kc += 32) {
            short8 a = *(const short8*)((const char*)atile +
                        ((ar * 256 + (kc + ak) * 2) ^ ((ar & 7) << 4)));
            #pragma unroll
            for (int nt = 0; nt < 4; ++nt) {
                int col = ncol + nt * 16 + (lane & 15);
                int boff = (col * 256 + (kc + ak) * 2) ^ ((col & 7) << 4);
                short8 bh = *(const short8*)((const char*)bt_hi + boff);
                acc[nt] = __builtin_amdgcn_mfma_f32_16x16x32_bf16(a, bh, acc[nt], 0, 0, 0);
                short8 bl = *(const short8*)((const char*)bt_lo + boff);
                acc[nt] = __builtin_amdgcn_mfma_f32_16x16x32_bf16(a, bl, acc[nt], 0, 0, 0);
            }
        }

        // ---- store C as bf16 ----
        #pragma unroll
        for (int nt = 0; nt < 4; ++nt) {
            #pragma unroll
            for (int r = 0; r < 4; ++r) {
                int node = node0 + mrow + (lane >> 4) * 4 + r;
                if (node < N_NODES)
                    Hout[(size_t)node * 128 + ncol + nt * 16 + (lane & 15)] = f2bf(acc[nt][r]);
            }
        }
    }
}

// ---------------- CSR gather (bf16 in/out) + fused epilogue ----------------

__global__ __launch_bounds__(256) void gather_kernel(const unsigned short* __restrict__ H,
                                                     const int* __restrict__ rs,
                                                     const int2* __restrict__ pairs,
                                                     const float* __restrict__ dinv,
                                                     const float* __restrict__ bias,
                                                     unsigned short* __restrict__ out) {
    int node = blockIdx.x * 4 + (threadIdx.x >> 6);
    if (node >= N_NODES) return;
    int lane = threadIdx.x & 63;

    float di = dinv[node];
    ushort2 hv = *(const ushort2*)&H[(size_t)node * 128 + lane * 2];
    float2 bb = *(const float2*)&bias[lane * 2];
    float ax = bf2f(hv.x) * di * di + bb.x;
    float ay = bf2f(hv.y) * di * di + bb.y;

    int beg = rs[node];
    int end = rs[node + 1];
    int i = beg;
    for (; i + 3 < end; i += 4) {
        int2 p0 = pairs[i];
        int2 p1 = pairs[i + 1];
        int2 p2 = pairs[i + 2];
        int2 p3 = pairs[i + 3];
        ushort2 h0 = *(const ushort2*)&H[(size_t)p0.x * 128 + lane * 2];
        ushort2 h1 = *(const ushort2*)&H[(size_t)p1.x * 128 + lane * 2];
        ushort2 h2 = *(const ushort2*)&H[(size_t)p2.x * 128 + lane * 2];
        ushort2 h3 = *(const ushort2*)&H[(size_t)p3.x * 128 + lane * 2];
        float w0 = __int_as_float(p0.y), w1 = __int_as_float(p1.y);
        float w2 = __int_as_float(p2.y), w3 = __int_as_float(p3.y);
        ax = fmaf(bf2f(h0.x), w0, ax); ay = fmaf(bf2f(h0.y), w0, ay);
        ax = fmaf(bf2f(h1.x), w1, ax); ay = fmaf(bf2f(h1.y), w1, ay);
        ax = fmaf(bf2f(h2.x), w2, ax); ay = fmaf(bf2f(h2.y), w2, ay);
        ax = fmaf(bf2f(h3.x), w3, ax); ay = fmaf(bf2f(h3.y), w3, ay);
    }
    for (; i < end; ++i) {
        int2 p = pairs[i];
        float w = __int_as_float(p.y);
        ushort2 h = *(const ushort2*)&H[(size_t)p.x * 128 + lane * 2];
        ax = fmaf(bf2f(h.x), w, ax);
        ay = fmaf(bf2f(h.y), w, ay);
    }
    ushort2 o;
    o.x = f2bf(fmaxf(ax, 0.f));
    o.y = f2bf(fmaxf(ay, 0.f));
    *(ushort2*)&out[(size_t)node * 128 + lane * 2] = o;
}

// ---------------- mean pool: dense segmented sum over start[] --------------
// grid = NG * 16 sub-blocks, 256 thr. slot = t&15 (8 feats), node-lane = t>>4.

__global__ __launch_bounds__(256) void pool_kernel(const unsigned short* __restrict__ H,
                                                   const int* __restrict__ start,
                                                   float* __restrict__ sums) {
    __shared__ float red[16][132];   // padded: 4-way max conflict on tiny reduce
    int g = blockIdx.x >> 4;
    int s = blockIdx.x & 15;
    int n0 = start[g], n1 = start[g + 1];
    int slot = threadIdx.x & 15;
    int nl = threadIdx.x >> 4;

    float acc[8];
    #pragma unroll
    for (int j = 0; j < 8; ++j) acc[j] = 0.f;

    for (int node = n0 + s * 16 + nl; node < n1; node += 256) {
        short8 v = *(const short8*)&H[(size_t)node * 128 + slot * 8];
        #pragma unroll
        for (int j = 0; j < 8; ++j) acc[j] += bf2f((unsigned short)v[j]);
    }

    #pragma unroll
    for (int j = 0; j < 8; ++j) red[nl][slot * 8 + j] = acc[j];
    __syncthreads();
    #pragma unroll
    for (int off = 8; off > 0; off >>= 1) {
        if (nl < off) {
            #pragma unroll
            for (int j = 0; j < 8; ++j)
                red[nl][slot * 8 + j] += red[nl + off][slot * 8 + j];
        }
        __syncthreads();
    }
    if (nl == 0) {
        #pragma unroll
        for (int j = 0; j < 8; ++j)
            unsafeAtomicAdd(&sums[g * D + slot * 8 + j], red[0][slot * 8 + j]);
    }
}

// ---------------- final FC ----------------

__global__ void fc_kernel(const float* __restrict__ sums, const int* __restrict__ start,
                          const float* __restrict__ Wfc, const float* __restrict__ bfc,
                          float* __restrict__ out) {
    __shared__ __align__(16) float ps[D];
    int g = blockIdx.x;
    int f = threadIdx.x;
    float c = (float)max(start[g + 1] - start[g], 1);
    ps[f] = sums[g * D + f] / c;
    __syncthreads();
    float acc = bfc[f];
    #pragma unroll
    for (int k = 0; k < D; k += 4) {
        float4 pv = *(const float4*)&ps[k];
        acc += pv.x * Wfc[k * D + f] + pv.y * Wfc[(k + 1) * D + f] +
               pv.z * Wfc[(k + 2) * D + f] + pv.w * Wfc[(k + 3) * D + f];
    }
    out[g * D + f] = acc;
}

extern "C" void kernel_launch(void* const* d_in, const int* in_sizes, int n_in,
                              void* d_out, int out_size, void* d_ws, size_t ws_size,
                              hipStream_t stream) {
    const float* x   = (const float*)d_in[0];
    const int* ei    = (const int*)d_in[1];   // [2, E]
    const int* batch = (const int*)d_in[2];
    const float* W1  = (const float*)d_in[3];
    const float* b1  = (const float*)d_in[4];
    const float* W2  = (const float*)d_in[5];
    const float* b2  = (const float*)d_in[6];
    const float* Wfc = (const float*)d_in[7];
    const float* bfc = (const float*)d_in[8];
    float* out = (float*)d_out;

    const int* src = ei;
    const int* dst = ei + N_EDGES;

    // workspace layout
    int2* pairs          = (int2*)d_ws;                          // E
    unsigned short* H1   = (unsigned short*)(pairs + N_EDGES);   // N*D bf16
    unsigned short* H2   = H1 + (size_t)N_NODES * D;             // N*D bf16
    float* dinv          = (float*)(H2 + (size_t)N_NODES * D);   // N
    int*   deg           = (int*)(dinv + N_NODES);               // N
    int*   rs            = deg + N_NODES;                        // N+4
    int*   cursor        = rs + N_NODES + 4;                     // N
    int*   bsum          = cursor + N_NODES;                     // 512
    int*   start         = bsum + 512;                           // NG+1 (+pad)
    float* sums          = (float*)(start + NG + 8);             // NG*D

    hipMemsetAsync(deg, 0, N_NODES * sizeof(int), stream);
    hipMemsetAsync(cursor, 0, N_NODES * sizeof(int), stream);
    hipMemsetAsync(sums, 0, NG * D * sizeof(float), stream);

    // --- CSR build (shared by both layers) + graph bounds ---
    hist_kernel<<<(N_EDGES + 255) / 256, 256, 0, stream>>>(dst, deg);
    dinv_kernel<<<(N_NODES + 255) / 256, 256, 0, stream>>>(deg, dinv);
    scan1_kernel<<<SCAN_NB, 256, 0, stream>>>(deg, rs, bsum);
    scan2_kernel<<<1, 512, 0, stream>>>(bsum);
    scan3_kernel<<<SCAN_NB, 256, 0, stream>>>(rs, bsum);
    fill_kernel<<<(N_EDGES + 255) / 256, 256, 0, stream>>>(src, dst, dinv, rs, cursor, pairs);
    bounds_kernel<<<1, 128, 0, stream>>>(batch, start);

    // --- layer 1 ---
    xw_mfma_kernel<true><<<512, 512, 0, stream>>>(x, W1, H1);
    gather_kernel<<<(N_NODES + 3) / 4, 256, 0, stream>>>(H1, rs, pairs, dinv, b1, H2);

    // --- layer 2 ---
    xw_mfma_kernel<false><<<512, 512, 0, stream>>>(H2, W2, H1);
    gather_kernel<<<(N_NODES + 3) / 4, 256, 0, stream>>>(H1, rs, pairs, dinv, b2, H2);

    // --- mean pool + FC ---
    pool_kernel<<<NG * 16, 256, 0, stream>>>(H2, start, sums);
    fc_kernel<<<NG, 128, 0, stream>>>(sums, start, Wfc, bfc, out);
}